// Round 14
// baseline (250.877 us; speedup 1.0000x reference)
//
#include <hip/hip_runtime.h>

#define NTOK 4096
#define DIMC 1024
#define HEADS 12
#define DH 8
#define QSCALE 0.35355339059327373f   /* 8^-0.5 */
#define LOG2E  1.4426950408889634f
#define LN2    0.6931471805599453f
#define QPRE   (QSCALE * LOG2E)       /* fold log2e into q prescale */

typedef float f4 __attribute__((ext_vector_type(4)));
typedef float f2 __attribute__((ext_vector_type(2)));

// ws layout (floats):
//   Q:  [h][n][8]        (pre-scaled by QPRE), offset 0,    12*4096*8
//   K:  [h][16][8][256]  chunk-tiled SoA,      offset KOFF, 12*8*4096
#define KOFF (HEADS * NTOK * DH)

// ---------------- Kernel 1: proj = x @ W^T -> q (AoS, scaled), k (tiled) ---
__global__ __launch_bounds__(256) void k1_proj(const float* __restrict__ x,
                                               const float* __restrict__ W,
                                               float* __restrict__ qk) {
    __shared__ float xs[8 * 1028];         // pad 1024->1028 breaks bank aliasing
    const int t = threadIdx.x;
    const int row0 = blockIdx.x * 8;

    const f4* x4 = (const f4*)(x + (size_t)row0 * DIMC);
    #pragma unroll
    for (int i = 0; i < 8; ++i) {
        int f = t + i * 256;
        int r = f >> 8;
        int c4 = f & 255;
        f4 v = x4[f];
        *(f4*)(&xs[r * 1028 + c4 * 4]) = v;
    }
    __syncthreads();

    const int g  = t >> 2;                 // 0..63 -> owns o = 3g..3g+2
    const int rg = t & 3;                  // owns rows rg*2 .. rg*2+1

    f2 acc[2][3];
    #pragma unroll
    for (int a = 0; a < 2; ++a)
        #pragma unroll
        for (int m = 0; m < 3; ++m) acc[a][m] = (f2)(0.f);

    const float* w0 = W + (size_t)(3 * g) * DIMC;
    #pragma unroll 2
    for (int c = 0; c < DIMC; c += 4) {
        f4 w[3];
        #pragma unroll
        for (int m = 0; m < 3; ++m)
            w[m] = *(const f4*)(w0 + (size_t)m * DIMC + c);
        #pragma unroll
        for (int a = 0; a < 2; ++a) {
            f4 xv = *(const f4*)(&xs[(rg * 2 + a) * 1028 + c]);
            #pragma unroll
            for (int m = 0; m < 3; ++m) {
                acc[a][m] = __builtin_elementwise_fma(xv.xy, w[m].xy, acc[a][m]);
                acc[a][m] = __builtin_elementwise_fma(xv.zw, w[m].zw, acc[a][m]);
            }
        }
    }

    #pragma unroll
    for (int m = 0; m < 3; ++m) {
        int o   = 3 * g + m;
        int qkf = (o >= 96) ? 1 : 0;
        int oo  = o - 96 * qkf;
        int h   = oo >> 3;
        int d   = oo & 7;
        #pragma unroll
        for (int a = 0; a < 2; ++a) {
            int n = row0 + rg * 2 + a;
            float v = acc[a][m].x + acc[a][m].y;
            if (!qkf) {
                qk[((size_t)h * NTOK + n) * DH + d] = v * QPRE;        // Q AoS
            } else {
                qk[KOFF + (((size_t)h * 16 + (n >> 8)) * DH + d) * 256 + (n & 255)] = v;
            }
        }
    }
}

// ---------------- Kernel 2: 1 MB slab per block, 3 blocks/CU ---------------
// Each block owns 64 consecutive rows (8 passes x 8 rows, R7 inner body).
// 48 KiB LDS pad caps residency at 3 blocks/CU -> few, long-lived write
// streams per CU (fillBuffer-like) instead of ~32 short-lived ones.
__device__ __forceinline__ float lsig2(float u) {
    // logsigmoid in log2 units: min(u,0) - log2(1 + 2^-|u|)   (u = s*log2e)
    float mn = fminf(u, 0.f);
    float z  = __builtin_amdgcn_exp2f(-fabsf(u));   // -|u| is a free modifier
    return mn - __builtin_amdgcn_logf(1.f + z);     // v_log_f32 = log2
}

__global__ __launch_bounds__(256) void k2_gates(const float* __restrict__ qk,
                                                float* __restrict__ out) {
    __shared__ float pad_[12288];           // 48 KiB -> 3 blocks/CU
    if (threadIdx.x == 0) ((volatile float*)pad_)[0] = 0.f;

    const int bid  = blockIdx.x;
    const int h    = bid >> 6;              // 64 blocks per head
    const int s0   = (bid & 63) << 6;       // slab: 64 consecutive rows
    const int t    = threadIdx.x;
    const int lane = t & 63;
    const int wid  = t >> 6;

    const float* kh = qk + KOFF + (size_t)h * (16 * DH * 256) + 4 * lane;

    for (int pass = 0; pass < 8; ++pass) {
        const int r0 = s0 + pass * 8 + 2 * wid;   // this wave's row pair
        const int r1 = r0 + 1;

        const float* qrow = qk + ((size_t)h * NTOK + r0) * DH;
        f2 q0s[8], q1s[8];
        #pragma unroll
        for (int d = 0; d < 8; ++d) {
            q0s[d] = (f2)(qrow[d]);
            q1s[d] = (f2)(qrow[DH + d]);
        }

        float* o0 = out + ((size_t)h * NTOK + r0) * NTOK;
        float* o1 = o0 + NTOK;
        const int cb = r0 >> 8;             // boundary chunk

        // ---- strictly-upper chunks: zero stores ----------------------------
        f4 z = (f4)(0.f);
        for (int cc = 15; cc > cb; --cc) {
            const int j0 = cc * 256 + 4 * lane;
            __builtin_nontemporal_store(z, (f4*)(o0 + j0));
            __builtin_nontemporal_store(z, (f4*)(o1 + j0));
        }

        float carry0, carry1;

        // initial load: boundary chunk
        f4 kv[8];
        {
            const float* kc = kh + (size_t)cb * 2048;
            #pragma unroll
            for (int d = 0; d < 8; ++d) kv[d] = *(const f4*)(kc + d * 256);
        }

        // ---- boundary chunk: masked compute, prefetch next -----------------
        {
            const int j0 = cb * 256 + 4 * lane;

            f2 A0 = (f2)(0.f), B0 = (f2)(0.f), A1 = (f2)(0.f), B1 = (f2)(0.f);
            #pragma unroll
            for (int d = 0; d < 8; ++d) {
                A0 = __builtin_elementwise_fma(kv[d].xy, q0s[d], A0);
                B0 = __builtin_elementwise_fma(kv[d].zw, q0s[d], B0);
                A1 = __builtin_elementwise_fma(kv[d].xy, q1s[d], A1);
                B1 = __builtin_elementwise_fma(kv[d].zw, q1s[d], B1);
            }
            {
                const int cn = (cb > 0) ? (cb - 1) : 0;
                const float* kn = kh + (size_t)cn * 2048;
                #pragma unroll
                for (int d = 0; d < 8; ++d) kv[d] = *(const f4*)(kn + d * 256);
            }

            float g0[4], g1[4];
            g0[0] = (j0 + 0 < r0) ? lsig2(A0.x) : 0.f;
            g0[1] = (j0 + 1 < r0) ? lsig2(A0.y) : 0.f;
            g0[2] = (j0 + 2 < r0) ? lsig2(B0.x) : 0.f;
            g0[3] = (j0 + 3 < r0) ? lsig2(B0.y) : 0.f;
            g1[0] = (j0 + 0 < r1) ? lsig2(A1.x) : 0.f;
            g1[1] = (j0 + 1 < r1) ? lsig2(A1.y) : 0.f;
            g1[2] = (j0 + 2 < r1) ? lsig2(B1.x) : 0.f;
            g1[3] = (j0 + 3 < r1) ? lsig2(B1.y) : 0.f;

            g0[2] += g0[3]; g0[1] += g0[2]; g0[0] += g0[1];
            g1[2] += g1[3]; g1[1] += g1[2]; g1[0] += g1[1];
            const float t0 = g0[0], t1 = g1[0];
            float s0v = t0, s1v = t1;
            #pragma unroll
            for (int off = 1; off < 64; off <<= 1) {
                float v0 = __shfl_down(s0v, off, 64);
                float v1 = __shfl_down(s1v, off, 64);
                if (lane + off < 64) { s0v += v0; s1v += v1; }
            }
            const float base0 = s0v - t0;
            const float base1 = s1v - t1;
            carry0 = __builtin_amdgcn_readfirstlane(s0v);
            carry1 = __builtin_amdgcn_readfirstlane(s1v);

            f4 gv0 = {g0[0], g0[1], g0[2], g0[3]};
            f4 gv1 = {g1[0], g1[1], g1[2], g1[3]};
            __builtin_nontemporal_store((gv0 + base0) * LN2, (f4*)(o0 + j0));
            __builtin_nontemporal_store((gv1 + base1) * LN2, (f4*)(o1 + j0));
        }

        // ---- interior chunks: unmasked, descending, prefetch ---------------
        for (int cc = cb - 1; cc >= 0; --cc) {
            const int j0 = cc * 256 + 4 * lane;

            f2 A0 = (f2)(0.f), B0 = (f2)(0.f), A1 = (f2)(0.f), B1 = (f2)(0.f);
            #pragma unroll
            for (int d = 0; d < 8; ++d) {
                A0 = __builtin_elementwise_fma(kv[d].xy, q0s[d], A0);
                B0 = __builtin_elementwise_fma(kv[d].zw, q0s[d], B0);
                A1 = __builtin_elementwise_fma(kv[d].xy, q1s[d], A1);
                B1 = __builtin_elementwise_fma(kv[d].zw, q1s[d], B1);
            }
            {
                const int cn = (cc > 0) ? (cc - 1) : 0;
                const float* kn = kh + (size_t)cn * 2048;
                #pragma unroll
                for (int d = 0; d < 8; ++d) kv[d] = *(const f4*)(kn + d * 256);
            }

            float g0[4], g1[4];
            g0[0] = lsig2(A0.x); g0[1] = lsig2(A0.y);
            g0[2] = lsig2(B0.x); g0[3] = lsig2(B0.y);
            g1[0] = lsig2(A1.x); g1[1] = lsig2(A1.y);
            g1[2] = lsig2(B1.x); g1[3] = lsig2(B1.y);

            g0[2] += g0[3]; g0[1] += g0[2]; g0[0] += g0[1];
            g1[2] += g1[3]; g1[1] += g1[2]; g1[0] += g1[1];
            const float t0 = g0[0], t1 = g1[0];
            float s0v = t0, s1v = t1;
            #pragma unroll
            for (int off = 1; off < 64; off <<= 1) {
                float v0 = __shfl_down(s0v, off, 64);
                float v1 = __shfl_down(s1v, off, 64);
                if (lane + off < 64) { s0v += v0; s1v += v1; }
            }
            const float base0 = (s0v - t0) + carry0;
            const float base1 = (s1v - t1) + carry1;
            carry0 += __builtin_amdgcn_readfirstlane(s0v);
            carry1 += __builtin_amdgcn_readfirstlane(s1v);

            f4 gv0 = {g0[0], g0[1], g0[2], g0[3]};
            f4 gv1 = {g1[0], g1[1], g1[2], g1[3]};
            __builtin_nontemporal_store((gv0 + base0) * LN2, (f4*)(o0 + j0));
            __builtin_nontemporal_store((gv1 + base1) * LN2, (f4*)(o1 + j0));
        }
    }
}

extern "C" void kernel_launch(void* const* d_in, const int* in_sizes, int n_in,
                              void* d_out, int out_size, void* d_ws, size_t ws_size,
                              hipStream_t stream) {
    const float* x = (const float*)d_in[0];
    const float* W = (const float*)d_in[1];
    float* out = (float*)d_out;
    float* qk  = (float*)d_ws;               // 3 MB scratch

    hipLaunchKernelGGL(k1_proj, dim3(NTOK / 8), dim3(256), 0, stream, x, W, qk);
    hipLaunchKernelGGL(k2_gates, dim3(HEADS * 64), dim3(256), 0, stream, qk, out);
}

// Round 15
// 202.447 us; speedup vs baseline: 1.2392x; 1.2392x over previous
//
#include <hip/hip_runtime.h>

#define NTOK 4096
#define DIMC 1024
#define HEADS 12
#define DH 8
#define QSCALE 0.35355339059327373f   /* 8^-0.5 */
#define LOG2E  1.4426950408889634f
#define LN2    0.6931471805599453f
#define QPRE   (QSCALE * LOG2E)       /* fold log2e into q prescale */

typedef float f4 __attribute__((ext_vector_type(4)));
typedef float f2 __attribute__((ext_vector_type(2)));

// ws layout (floats):
//   Q:  [h][n][8]        (pre-scaled by QPRE), offset 0,    12*4096*8
//   K:  [h][16][8][256]  chunk-tiled SoA,      offset KOFF, 12*8*4096
#define KOFF (HEADS * NTOK * DH)

// ---------------- Kernel 1: proj = x @ W^T -> q (AoS, scaled), k (tiled) ---
__global__ __launch_bounds__(256) void k1_proj(const float* __restrict__ x,
                                               const float* __restrict__ W,
                                               float* __restrict__ qk) {
    __shared__ float xs[8 * 1028];         // pad 1024->1028 breaks bank aliasing
    const int t = threadIdx.x;
    const int row0 = blockIdx.x * 8;

    const f4* x4 = (const f4*)(x + (size_t)row0 * DIMC);
    #pragma unroll
    for (int i = 0; i < 8; ++i) {
        int f = t + i * 256;
        int r = f >> 8;
        int c4 = f & 255;
        f4 v = x4[f];
        *(f4*)(&xs[r * 1028 + c4 * 4]) = v;
    }
    __syncthreads();

    const int g  = t >> 2;                 // 0..63 -> owns o = 3g..3g+2
    const int rg = t & 3;                  // owns rows rg*2 .. rg*2+1

    f2 acc[2][3];
    #pragma unroll
    for (int a = 0; a < 2; ++a)
        #pragma unroll
        for (int m = 0; m < 3; ++m) acc[a][m] = (f2)(0.f);

    const float* w0 = W + (size_t)(3 * g) * DIMC;
    #pragma unroll 2
    for (int c = 0; c < DIMC; c += 4) {
        f4 w[3];
        #pragma unroll
        for (int m = 0; m < 3; ++m)
            w[m] = *(const f4*)(w0 + (size_t)m * DIMC + c);
        #pragma unroll
        for (int a = 0; a < 2; ++a) {
            f4 xv = *(const f4*)(&xs[(rg * 2 + a) * 1028 + c]);
            #pragma unroll
            for (int m = 0; m < 3; ++m) {
                acc[a][m] = __builtin_elementwise_fma(xv.xy, w[m].xy, acc[a][m]);
                acc[a][m] = __builtin_elementwise_fma(xv.zw, w[m].zw, acc[a][m]);
            }
        }
    }

    #pragma unroll
    for (int m = 0; m < 3; ++m) {
        int o   = 3 * g + m;
        int qkf = (o >= 96) ? 1 : 0;
        int oo  = o - 96 * qkf;
        int h   = oo >> 3;
        int d   = oo & 7;
        #pragma unroll
        for (int a = 0; a < 2; ++a) {
            int n = row0 + rg * 2 + a;
            float v = acc[a][m].x + acc[a][m].y;
            if (!qkf) {
                qk[((size_t)h * NTOK + n) * DH + d] = v * QPRE;        // Q AoS
            } else {
                qk[KOFF + (((size_t)h * 16 + (n >> 8)) * DH + d) * 256 + (n & 255)] = v;
            }
        }
    }
}

// ---------------- Kernel 2: 1 row/wave, 4-chunk groups, parallel scans -----
// Breaks the loop-carried carry chain: 4 chunks' wave-scans run with 4-way
// ILP (rounds outer), carries join once per group via 4 SALU readfirstlanes.
// Serial links per row drop from ~8.5 (one per chunk) to ~2.1 (one per group).
__device__ __forceinline__ float lsig2(float u) {
    // logsigmoid in log2 units: min(u,0) - log2(1 + 2^-|u|)   (u = s*log2e)
    float mn = fminf(u, 0.f);
    float z  = __builtin_amdgcn_exp2f(-fabsf(u));   // -|u| is a free modifier
    return mn - __builtin_amdgcn_logf(1.f + z);     // v_log_f32 = log2
}

__global__ __launch_bounds__(512) void k2_gates(const float* __restrict__ qk,
                                                float* __restrict__ out) {
    const int bid  = blockIdx.x;
    const int h    = bid >> 9;              // 512 blocks per head
    const int i0   = (bid & 511) << 3;      // 8 rows per block, 1 per wave
    const int t    = threadIdx.x;
    const int lane = t & 63;
    const int wid  = t >> 6;                // 0..7
    const int r    = i0 + wid;              // this wave's row

    const float* qp = qk + ((size_t)h * NTOK + r) * DH;
    f2 qs[8];
    #pragma unroll
    for (int d = 0; d < 8; ++d) qs[d] = (f2)(qp[d]);

    const float* kh = qk + KOFF + (size_t)h * (16 * DH * 256) + 4 * lane;
    float* o = out + ((size_t)h * NTOK + r) * NTOK;

    const int cb = r >> 8;                  // boundary chunk
    const int gb = cb >> 2;                 // boundary group of 4 chunks

    // ---- strictly-upper chunks: zero stores --------------------------------
    const f4 z = (f4)(0.f);
    for (int cc = 15; cc > cb; --cc)
        __builtin_nontemporal_store(z, (f4*)(o + cc * 256 + 4 * lane));

    // ---- computed chunks in groups of 4, descending ------------------------
    float carry = 0.f;
    for (int gi = gb; gi >= 0; --gi) {
        float gg[4][4], s[4], tot[4];

        // per-chunk dots + lsig + local suffix (independent across chunks;
        // liveness is wave-uniform so branches don't diverge)
        #pragma unroll
        for (int k = 3; k >= 0; --k) {
            const int cc = gi * 4 + k;
            if (cc > cb) {                   // dead chunk (only in top group)
                gg[k][0] = 0.f; gg[k][1] = 0.f; gg[k][2] = 0.f; gg[k][3] = 0.f;
                s[k] = 0.f; tot[k] = 0.f;
                continue;
            }
            const float* kc = kh + (size_t)cc * 2048;
            f4 kv[8];
            #pragma unroll
            for (int d = 0; d < 8; ++d) kv[d] = *(const f4*)(kc + d * 256);

            f2 A = (f2)(0.f), B = (f2)(0.f);
            #pragma unroll
            for (int d = 0; d < 8; ++d) {
                A = __builtin_elementwise_fma(kv[d].xy, qs[d], A);
                B = __builtin_elementwise_fma(kv[d].zw, qs[d], B);
            }

            float g0, g1, g2, g3;
            if (cc == cb) {                  // boundary: mask j < r
                const int j0 = cc * 256 + 4 * lane;
                g0 = (j0 + 0 < r) ? lsig2(A.x) : 0.f;
                g1 = (j0 + 1 < r) ? lsig2(A.y) : 0.f;
                g2 = (j0 + 2 < r) ? lsig2(B.x) : 0.f;
                g3 = (j0 + 3 < r) ? lsig2(B.y) : 0.f;
            } else {
                g0 = lsig2(A.x); g1 = lsig2(A.y);
                g2 = lsig2(B.x); g3 = lsig2(B.y);
            }
            g2 += g3; g1 += g2; g0 += g1;    // local reverse suffix
            gg[k][0] = g0; gg[k][1] = g1; gg[k][2] = g2; gg[k][3] = g3;
            tot[k] = g0; s[k] = g0;
        }

        // wave-wide suffix scans, rounds outer / 4 chunks inner (4-way ILP)
        #pragma unroll
        for (int off = 1; off < 64; off <<= 1) {
            float v0 = __shfl_down(s[0], off, 64);
            float v1 = __shfl_down(s[1], off, 64);
            float v2 = __shfl_down(s[2], off, 64);
            float v3 = __shfl_down(s[3], off, 64);
            if (lane + off < 64) { s[0] += v0; s[1] += v1; s[2] += v2; s[3] += v3; }
        }

        // carry combine: one short SALU pass per group (4 links -> 1)
        float base[4];
        float acc = carry;
        #pragma unroll
        for (int k = 3; k >= 0; --k) {
            base[k] = (s[k] - tot[k]) + acc;
            acc += __builtin_amdgcn_readfirstlane(s[k]);
        }
        carry = acc;

        // stores ascending (live chunks only; uniform branch)
        #pragma unroll
        for (int k = 0; k < 4; ++k) {
            const int cc = gi * 4 + k;
            if (cc <= cb) {
                f4 gv = {gg[k][0], gg[k][1], gg[k][2], gg[k][3]};
                __builtin_nontemporal_store((gv + base[k]) * LN2,
                                            (f4*)(o + cc * 256 + 4 * lane));
            }
        }
    }
}

extern "C" void kernel_launch(void* const* d_in, const int* in_sizes, int n_in,
                              void* d_out, int out_size, void* d_ws, size_t ws_size,
                              hipStream_t stream) {
    const float* x = (const float*)d_in[0];
    const float* W = (const float*)d_in[1];
    float* out = (float*)d_out;
    float* qk  = (float*)d_ws;               // 3 MB scratch

    hipLaunchKernelGGL(k1_proj, dim3(NTOK / 8), dim3(256), 0, stream, x, W, qk);
    hipLaunchKernelGGL(k2_gates, dim3(HEADS * NTOK / 8), dim3(512), 0, stream, qk, out);
}